// Round 1
// baseline (237.408 us; speedup 1.0000x reference)
//
#include <hip/hip_runtime.h>

typedef float  f32x4  __attribute__((ext_vector_type(4)));
typedef __bf16 bf16x8 __attribute__((ext_vector_type(8)));
typedef short  s16x8  __attribute__((ext_vector_type(8)));
typedef short  s16x4  __attribute__((ext_vector_type(4)));

static __device__ __forceinline__ unsigned short f2bf(float f) {
  return __builtin_bit_cast(unsigned short, (__bf16)f);
}
static __device__ __forceinline__ bf16x8 bc8(s16x8 v) {
  return __builtin_bit_cast(bf16x8, v);
}

// ---------------- cast x (fp32 -> bf16) ----------------
__global__ void cast_x_k(const float* __restrict__ x, unsigned short* __restrict__ xb) {
  int i = (blockIdx.x * 256 + threadIdx.x) * 8;
  float4 a = *(const float4*)(x + i);
  float4 b = *(const float4*)(x + i + 4);
  s16x8 o;
  o[0] = (short)f2bf(a.x); o[1] = (short)f2bf(a.y);
  o[2] = (short)f2bf(a.z); o[3] = (short)f2bf(a.w);
  o[4] = (short)f2bf(b.x); o[5] = (short)f2bf(b.y);
  o[6] = (short)f2bf(b.z); o[7] = (short)f2bf(b.w);
  *(s16x8*)(xb + i) = o;
}

// ------------- transpose W (1024x1024 fp32 k-major) -> WT bf16 (n-major) -------------
__global__ void transpose_w_k(const float* __restrict__ W0, const float* __restrict__ W1,
                              const float* __restrict__ W2, const float* __restrict__ W3,
                              unsigned short* __restrict__ wtb) {
  const float* W = blockIdx.z == 0 ? W0 : blockIdx.z == 1 ? W1 : blockIdx.z == 2 ? W2 : W3;
  unsigned short* out = wtb + (size_t)blockIdx.z * 1048576;
  __shared__ unsigned short tl[64][72];  // [n-local][k-local], 144B row (16B-mult)
  const int t = threadIdx.x;
  const int kt = blockIdx.y * 64, nt = blockIdx.x * 64;
  const int row = t >> 2, seg = t & 3;
  const float* src = W + (kt + row) * 1024 + nt + seg * 16;
#pragma unroll
  for (int q = 0; q < 4; ++q) {
    float4 v = *(const float4*)(src + q * 4);
    tl[seg * 16 + q * 4 + 0][row] = f2bf(v.x);
    tl[seg * 16 + q * 4 + 1][row] = f2bf(v.y);
    tl[seg * 16 + q * 4 + 2][row] = f2bf(v.z);
    tl[seg * 16 + q * 4 + 3][row] = f2bf(v.w);
  }
  __syncthreads();
  unsigned short* dst = out + (nt + row) * 1024 + kt + seg * 16;
  *(s16x8*)dst       = *(const s16x8*)&tl[row][seg * 16];
  *(s16x8*)(dst + 8) = *(const s16x8*)&tl[row][seg * 16 + 8];
}

// ---------------- GEMM: C(4096x1024) = A(bf16) @ WT^T + bias ----------------
// A: (4096,1024) bf16 k-contiguous. BT: (1024,1024) bf16 = W^T, k-contiguous.
// MODE 0: Q  -> outB bf16 (B,H,T,DH), *0.125
// MODE 1: K/V-> outB bf16 (B,H,T,DH) + outF fp32 (B,H,T,DH)
// MODE 2: O  -> outF fp32 (B,T,D)
static __device__ __forceinline__ int trans_ix(int m, int n) {
  int b = m >> 11, tt = m & 2047, h = n >> 6, dh = n & 63;
  return ((b << 4) + h) * 131072 + tt * 64 + dh;
}

template <int MODE>
__global__ __launch_bounds__(256) void gemm_k(const unsigned short* __restrict__ A,
                                              const unsigned short* __restrict__ BT,
                                              const float* __restrict__ bias,
                                              float* __restrict__ outF,
                                              unsigned short* __restrict__ outB) {
  // BM=64, BN=128, BK=32. 4 waves as 2x2 -> wave tile 32x64.
  __shared__ s16x8 aV[64 * 5];    // [row][kgroup], stride 5 vectors (pad)
  __shared__ s16x8 bV[128 * 5];
  const int t = threadIdx.x;
  const int lane = t & 63, ln = lane & 15, g = lane >> 4;
  const int w = t >> 6, wm = w >> 1, wn = w & 1;
  const int bm0 = blockIdx.y * 64, bn0 = blockIdx.x * 128;
  f32x4 acc[2][4] = {};

  const int arow = t >> 2, aseg = t & 3;          // A: 64 rows x 4 segs of 8
  const int brow = t >> 1, bhalf = t & 1;         // B: 128 rows x 2 halves of 16
  const unsigned short* aSrc = A + (bm0 + arow) * 1024 + aseg * 8;
  const unsigned short* bSrc = BT + (bn0 + brow) * 1024 + bhalf * 16;

  s16x8 ra  = *(const s16x8*)(aSrc);
  s16x8 rb0 = *(const s16x8*)(bSrc);
  s16x8 rb1 = *(const s16x8*)(bSrc + 8);

  for (int kk = 0; kk < 1024; kk += 32) {
    __syncthreads();
    aV[arow * 5 + aseg] = ra;
    bV[brow * 5 + bhalf * 2]     = rb0;
    bV[brow * 5 + bhalf * 2 + 1] = rb1;
    if (kk + 32 < 1024) {
      ra  = *(const s16x8*)(aSrc + kk + 32);
      rb0 = *(const s16x8*)(bSrc + kk + 32);
      rb1 = *(const s16x8*)(bSrc + kk + 40);
    }
    __syncthreads();
    bf16x8 af[2], bfv[4];
#pragma unroll
    for (int mi = 0; mi < 2; ++mi) af[mi] = bc8(aV[(wm * 32 + mi * 16 + ln) * 5 + g]);
#pragma unroll
    for (int ni = 0; ni < 4; ++ni) bfv[ni] = bc8(bV[(wn * 64 + ni * 16 + ln) * 5 + g]);
#pragma unroll
    for (int mi = 0; mi < 2; ++mi)
#pragma unroll
      for (int ni = 0; ni < 4; ++ni)
        acc[mi][ni] = __builtin_amdgcn_mfma_f32_16x16x32_bf16(af[mi], bfv[ni], acc[mi][ni], 0, 0, 0);
  }

  float bs[4];
#pragma unroll
  for (int ni = 0; ni < 4; ++ni) bs[ni] = bias[bn0 + wn * 64 + ni * 16 + ln];
#pragma unroll
  for (int mi = 0; mi < 2; ++mi)
#pragma unroll
    for (int ni = 0; ni < 4; ++ni)
#pragma unroll
      for (int r = 0; r < 4; ++r) {
        int m = bm0 + wm * 32 + mi * 16 + g * 4 + r;
        int n = bn0 + wn * 64 + ni * 16 + ln;
        float v = acc[mi][ni][r] + bs[ni];
        if (MODE == 0) {
          outB[trans_ix(m, n)] = f2bf(v * 0.125f);
        } else if (MODE == 1) {
          int ix = trans_ix(m, n);
          outB[ix] = f2bf(v);
          outF[ix] = v;
        } else {
          outF[m * 1024 + n] = v;
        }
      }
}

// ---------------- flash attention ----------------
// qb/kb/vb: (B*H, T, DH) bf16; q pre-scaled by 0.125. ob: (B, T, H*DH) bf16.
__global__ __launch_bounds__(256) void attn_k(const unsigned short* __restrict__ qb,
                                              const unsigned short* __restrict__ kb,
                                              const unsigned short* __restrict__ vb,
                                              unsigned short* __restrict__ ob) {
  __shared__ s16x8 kV[64 * 9];    // [kv][dh] padded: row stride 9 vectors (144B)
  __shared__ s16x8 vtV[64 * 9];   // [dh][kv] transposed, same padding
  __shared__ s16x8 pV[64 * 9];    // [q-local][kv] wave-private rows
  const int t = threadIdx.x;
  const int lane = t & 63, ln = lane & 15, g = lane >> 4;
  const int w = t >> 6;
  const int q0 = blockIdx.x * 64;
  const int bh = blockIdx.y;
  const unsigned short* Qp = qb + (size_t)bh * 131072;
  const unsigned short* Kp = kb + (size_t)bh * 131072;
  const unsigned short* Vp = vb + (size_t)bh * 131072;

  bf16x8 qf[2];
  {
    const unsigned short* qrow = Qp + (q0 + w * 16 + ln) * 64 + g * 8;
    qf[0] = bc8(*(const s16x8*)qrow);
    qf[1] = bc8(*(const s16x8*)(qrow + 32));
  }
  f32x4 o[4] = {};
  float mrow[4] = {-1e30f, -1e30f, -1e30f, -1e30f};
  float lrow[4] = {0.f, 0.f, 0.f, 0.f};
  const int ntile = q0 / 64 + 1;
  const int krow = t >> 2, kseg = t & 3;
  const int kvb_ = t >> 4, dhb = t & 15;

  for (int tile = 0; tile < ntile; ++tile) {
    const int kv0 = tile * 64;
    __syncthreads();
    {  // K stage (linear)
      const s16x8* src = (const s16x8*)(Kp + (kv0 + krow) * 64 + kseg * 16);
      kV[krow * 9 + kseg * 2]     = src[0];
      kV[krow * 9 + kseg * 2 + 1] = src[1];
    }
    {  // V stage (transposed 4x4 blocks)
      s16x4 vj[4];
#pragma unroll
      for (int j = 0; j < 4; ++j)
        vj[j] = *(const s16x4*)(Vp + (kv0 + kvb_ * 4 + j) * 64 + dhb * 4);
#pragma unroll
      for (int d = 0; d < 4; ++d) {
        s16x4 wv;
        wv[0] = vj[0][d]; wv[1] = vj[1][d]; wv[2] = vj[2][d]; wv[3] = vj[3][d];
        *(s16x4*)((short*)vtV + (dhb * 4 + d) * 72 + kvb_ * 4) = wv;
      }
    }
    __syncthreads();

    // S = Q K^T (q pre-scaled)
    f32x4 s4[4] = {};
#pragma unroll
    for (int st = 0; st < 2; ++st)
#pragma unroll
      for (int f = 0; f < 4; ++f) {
        bf16x8 kf = bc8(kV[(f * 16 + ln) * 9 + st * 4 + g]);
        s4[f] = __builtin_amdgcn_mfma_f32_16x16x32_bf16(qf[st], kf, s4[f], 0, 0, 0);
      }
    if (tile == ntile - 1) {  // diagonal tile: mask kv > q
#pragma unroll
      for (int f = 0; f < 4; ++f)
#pragma unroll
        for (int r = 0; r < 4; ++r)
          if (f * 16 + ln > w * 16 + g * 4 + r) s4[f][r] = -1e30f;
    }

    // online softmax (rows live in 16-lane groups)
    f32x4 p4[4];
#pragma unroll
    for (int r = 0; r < 4; ++r) {
      float mt = fmaxf(fmaxf(s4[0][r], s4[1][r]), fmaxf(s4[2][r], s4[3][r]));
#pragma unroll
      for (int off = 1; off < 16; off <<= 1) mt = fmaxf(mt, __shfl_xor(mt, off));
      float mn = fmaxf(mrow[r], mt);
      float alpha = __expf(mrow[r] - mn);
      float ps = 0.f;
#pragma unroll
      for (int f = 0; f < 4; ++f) {
        float pv = __expf(s4[f][r] - mn);
        p4[f][r] = pv;
        ps += pv;
      }
#pragma unroll
      for (int off = 1; off < 16; off <<= 1) ps += __shfl_xor(ps, off);
      lrow[r] = lrow[r] * alpha + ps;
      mrow[r] = mn;
#pragma unroll
      for (int f = 0; f < 4; ++f) o[f][r] *= alpha;
    }

    // P -> wave-private LDS rows (no barrier needed: intra-wave, in-order DS)
    short* pB = (short*)pV;
#pragma unroll
    for (int f = 0; f < 4; ++f)
#pragma unroll
      for (int r = 0; r < 4; ++r)
        pB[(w * 16 + g * 4 + r) * 72 + f * 16 + ln] = (short)f2bf(p4[f][r]);

    // O += P V
#pragma unroll
    for (int st = 0; st < 2; ++st) {
      bf16x8 pa = bc8(pV[(w * 16 + ln) * 9 + st * 4 + g]);
#pragma unroll
      for (int f = 0; f < 4; ++f) {
        bf16x8 vf = bc8(vtV[(f * 16 + ln) * 9 + st * 4 + g]);
        o[f] = __builtin_amdgcn_mfma_f32_16x16x32_bf16(pa, vf, o[f], 0, 0, 0);
      }
    }
  }

  const int b = bh >> 4, h = bh & 15;
#pragma unroll
  for (int f = 0; f < 4; ++f)
#pragma unroll
    for (int r = 0; r < 4; ++r) {
      int q = q0 + w * 16 + g * 4 + r;
      int dh = f * 16 + ln;
      ob[((size_t)b * 2048 + q) * 1024 + h * 64 + dh] = f2bf(o[f][r] / lrow[r]);
    }
}

extern "C" void kernel_launch(void* const* d_in, const int* in_sizes, int n_in,
                              void* d_out, int out_size, void* d_ws, size_t ws_size,
                              hipStream_t stream) {
  (void)in_sizes; (void)n_in; (void)out_size; (void)ws_size;
  const float* x  = (const float*)d_in[0];
  const float* Wq = (const float*)d_in[1];
  const float* bq = (const float*)d_in[2];
  const float* Wk = (const float*)d_in[3];
  const float* bk = (const float*)d_in[4];
  const float* Wv = (const float*)d_in[5];
  const float* bv = (const float*)d_in[6];
  const float* Wo = (const float*)d_in[7];
  const float* bo = (const float*)d_in[8];
  float* out = (float*)d_out;

  unsigned short* ws  = (unsigned short*)d_ws;
  unsigned short* xb  = ws;                      // 4,194,304 bf16
  unsigned short* wtb = ws + 4194304;            // 4 x 1,048,576 bf16 (Wq^T,Wk^T,Wv^T,Wo^T)
  unsigned short* qb  = ws + 8388608;            // 4,194,304
  unsigned short* kb  = qb + 4194304;
  unsigned short* vb  = kb + 4194304;
  unsigned short* ab  = vb + 4194304;            // attn out (B,T,D) bf16; total 48 MB

  cast_x_k<<<2048, 256, 0, stream>>>(x, xb);
  transpose_w_k<<<dim3(16, 16, 4), 256, 0, stream>>>(Wq, Wk, Wv, Wo, wtb);
  gemm_k<0><<<dim3(8, 64), 256, 0, stream>>>(xb, wtb,           bq, nullptr,       qb);
  gemm_k<1><<<dim3(8, 64), 256, 0, stream>>>(xb, wtb + 1048576, bk, out + 4194304, kb);
  gemm_k<1><<<dim3(8, 64), 256, 0, stream>>>(xb, wtb + 2097152, bv, out + 8388608, vb);
  attn_k<<<dim3(32, 32), 256, 0, stream>>>(qb, kb, vb, ab);
  gemm_k<2><<<dim3(8, 64), 256, 0, stream>>>(ab, wtb + 3145728, bo, out, nullptr);
}

// Round 3
// 153.266 us; speedup vs baseline: 1.5490x; 1.5490x over previous
//
#include <hip/hip_runtime.h>

typedef float  f32x4  __attribute__((ext_vector_type(4)));
typedef __bf16 bf16x8 __attribute__((ext_vector_type(8)));
typedef short  s16x8  __attribute__((ext_vector_type(8)));
typedef short  s16x4  __attribute__((ext_vector_type(4)));

static __device__ __forceinline__ unsigned short f2bf(float f) {
  return __builtin_bit_cast(unsigned short, (__bf16)f);
}
static __device__ __forceinline__ bf16x8 bc8(s16x8 v) {
  return __builtin_bit_cast(bf16x8, v);
}

// ---------------- cast x (fp32 -> bf16) ----------------
__global__ void cast_x_k(const float* __restrict__ x, unsigned short* __restrict__ xb) {
  int i = (blockIdx.x * 256 + threadIdx.x) * 8;
  float4 a = *(const float4*)(x + i);
  float4 b = *(const float4*)(x + i + 4);
  s16x8 o;
  o[0] = (short)f2bf(a.x); o[1] = (short)f2bf(a.y);
  o[2] = (short)f2bf(a.z); o[3] = (short)f2bf(a.w);
  o[4] = (short)f2bf(b.x); o[5] = (short)f2bf(b.y);
  o[6] = (short)f2bf(b.z); o[7] = (short)f2bf(b.w);
  *(s16x8*)(xb + i) = o;
}

// ------------- transpose W (1024x1024 fp32 k-major) -> WT bf16 (n-major) -------------
__global__ void transpose_w_k(const float* __restrict__ W0, const float* __restrict__ W1,
                              const float* __restrict__ W2, const float* __restrict__ W3,
                              unsigned short* __restrict__ wtb) {
  const float* W = blockIdx.z == 0 ? W0 : blockIdx.z == 1 ? W1 : blockIdx.z == 2 ? W2 : W3;
  unsigned short* out = wtb + (size_t)blockIdx.z * 1048576;
  __shared__ unsigned short tl[64][72];
  const int t = threadIdx.x;
  const int kt = blockIdx.y * 64, nt = blockIdx.x * 64;
  const int row = t >> 2, seg = t & 3;
  const float* src = W + (kt + row) * 1024 + nt + seg * 16;
#pragma unroll
  for (int q = 0; q < 4; ++q) {
    float4 v = *(const float4*)(src + q * 4);
    tl[seg * 16 + q * 4 + 0][row] = f2bf(v.x);
    tl[seg * 16 + q * 4 + 1][row] = f2bf(v.y);
    tl[seg * 16 + q * 4 + 2][row] = f2bf(v.z);
    tl[seg * 16 + q * 4 + 3][row] = f2bf(v.w);
  }
  __syncthreads();
  unsigned short* dst = out + (nt + row) * 1024 + kt + seg * 16;
  *(s16x8*)dst       = *(const s16x8*)&tl[row][seg * 16];
  *(s16x8*)(dst + 8) = *(const s16x8*)&tl[row][seg * 16 + 8];
}

// ---------------- GEMM: C(4096x1024) = A(bf16) @ WT^T + bias ----------------
static __device__ __forceinline__ int trans_ix(int m, int n) {
  int b = m >> 11, tt = m & 2047, h = n >> 6, dh = n & 63;
  return ((b << 4) + h) * 131072 + tt * 64 + dh;
}

template <int MODE>
__global__ __launch_bounds__(256) void gemm_k(const unsigned short* __restrict__ A,
                                              const unsigned short* __restrict__ BT,
                                              const float* __restrict__ bias,
                                              float* __restrict__ outF,
                                              unsigned short* __restrict__ outB) {
  __shared__ s16x8 aV[64 * 5];
  __shared__ s16x8 bV[128 * 5];
  const int t = threadIdx.x;
  const int lane = t & 63, ln = lane & 15, g = lane >> 4;
  const int w = t >> 6, wm = w >> 1, wn = w & 1;
  const int bm0 = blockIdx.y * 64, bn0 = blockIdx.x * 128;
  f32x4 acc[2][4] = {};

  const int arow = t >> 2, aseg = t & 3;
  const int brow = t >> 1, bhalf = t & 1;
  const unsigned short* aSrc = A + (bm0 + arow) * 1024 + aseg * 8;
  const unsigned short* bSrc = BT + (bn0 + brow) * 1024 + bhalf * 16;

  s16x8 ra  = *(const s16x8*)(aSrc);
  s16x8 rb0 = *(const s16x8*)(bSrc);
  s16x8 rb1 = *(const s16x8*)(bSrc + 8);

  for (int kk = 0; kk < 1024; kk += 32) {
    __syncthreads();
    aV[arow * 5 + aseg] = ra;
    bV[brow * 5 + bhalf * 2]     = rb0;
    bV[brow * 5 + bhalf * 2 + 1] = rb1;
    if (kk + 32 < 1024) {
      ra  = *(const s16x8*)(aSrc + kk + 32);
      rb0 = *(const s16x8*)(bSrc + kk + 32);
      rb1 = *(const s16x8*)(bSrc + kk + 40);
    }
    __syncthreads();
    bf16x8 af[2], bfv[4];
#pragma unroll
    for (int mi = 0; mi < 2; ++mi) af[mi] = bc8(aV[(wm * 32 + mi * 16 + ln) * 5 + g]);
#pragma unroll
    for (int ni = 0; ni < 4; ++ni) bfv[ni] = bc8(bV[(wn * 64 + ni * 16 + ln) * 5 + g]);
#pragma unroll
    for (int mi = 0; mi < 2; ++mi)
#pragma unroll
      for (int ni = 0; ni < 4; ++ni)
        acc[mi][ni] = __builtin_amdgcn_mfma_f32_16x16x32_bf16(af[mi], bfv[ni], acc[mi][ni], 0, 0, 0);
  }

  float bs[4];
#pragma unroll
  for (int ni = 0; ni < 4; ++ni) bs[ni] = bias[bn0 + wn * 64 + ni * 16 + ln];
#pragma unroll
  for (int mi = 0; mi < 2; ++mi)
#pragma unroll
    for (int ni = 0; ni < 4; ++ni)
#pragma unroll
      for (int r = 0; r < 4; ++r) {
        int m = bm0 + wm * 32 + mi * 16 + g * 4 + r;
        int n = bn0 + wn * 64 + ni * 16 + ln;
        float v = acc[mi][ni][r] + bs[ni];
        if (MODE == 0) {
          outB[trans_ix(m, n)] = f2bf(v * 0.125f);
        } else if (MODE == 1) {
          int ix = trans_ix(m, n);
          outB[ix] = f2bf(v);
          outF[ix] = v;
        } else {
          outF[m * 1024 + n] = v;
        }
      }
}

// ---------------- flash attention v2 (bugfixed) ----------------
// Swapped-operand layout: S^T = mfma(K,Q) so each lane owns one q-row (q = lane&15).
// O accumulated transposed: O^T = mfma(V^T, P).
// Block: 4 waves x 16 q-rows; processes q-tiles {bx, 31-bx} (33 KV-units each).
// K/V double-buffered in LDS, prefetch issued before compute, 1 barrier per KV tile.
__global__ __launch_bounds__(256) void attn_k(const unsigned short* __restrict__ qb,
                                              const unsigned short* __restrict__ kb,
                                              const unsigned short* __restrict__ vb,
                                              unsigned short* __restrict__ ob) {
  __shared__ s16x8 kV[2 * 64 * 9];   // [buf][kv][dh] rows padded to 144B
  __shared__ s16x8 vtV[2 * 64 * 9];  // [buf][dh][kv] transposed; per-buf = 4608 shorts
  __shared__ s16x8 pV[64 * 9];       // [q-local][kv] wave-private rows
  const int t = threadIdx.x;
  const int lane = t & 63, ln = lane & 15, g = lane >> 4;
  const int w = t >> 6;
  const int bh = blockIdx.y;
  const int b = bh >> 4, h = bh & 15;
  const unsigned short* Qp = qb + (size_t)bh * 131072;
  const unsigned short* Kp = kb + (size_t)bh * 131072;
  const unsigned short* Vp = vb + (size_t)bh * 131072;

  const int krow = t >> 2, kseg = t & 3;   // K stage mapping
  const int kvb_ = t >> 4, dhb = t & 15;   // V stage mapping

  for (int half = 0; half < 2; ++half) {
    const int qblk = half == 0 ? (int)blockIdx.x : 31 - (int)blockIdx.x;
    const int q0 = qblk * 64;
    const int ntile = qblk + 1;

    bf16x8 qf[2];
    {
      const unsigned short* qrow = Qp + (q0 + w * 16 + ln) * 64 + g * 8;
      qf[0] = bc8(*(const s16x8*)qrow);
      qf[1] = bc8(*(const s16x8*)(qrow + 32));
    }
    f32x4 o[4] = {};
    float mrow = -1e30f, lrow = 0.f;

    // prologue: stage tile 0 into buf 0
    __syncthreads();  // protect LDS from previous half's readers
    {
      const s16x8* ks = (const s16x8*)(Kp + krow * 64 + kseg * 16);
      kV[krow * 9 + kseg * 2]     = ks[0];
      kV[krow * 9 + kseg * 2 + 1] = ks[1];
      s16x4 vj[4];
#pragma unroll
      for (int j = 0; j < 4; ++j)
        vj[j] = *(const s16x4*)(Vp + (kvb_ * 4 + j) * 64 + dhb * 4);
#pragma unroll
      for (int d = 0; d < 4; ++d) {
        s16x4 wv;
        wv[0] = vj[0][d]; wv[1] = vj[1][d]; wv[2] = vj[2][d]; wv[3] = vj[3][d];
        *(s16x4*)((short*)vtV + (dhb * 4 + d) * 72 + kvb_ * 4) = wv;
      }
    }
    __syncthreads();

    for (int tile = 0; tile < ntile; ++tile) {
      const int buf = tile & 1;
      const bool pre = (tile + 1) < ntile;
      // issue next tile's global loads early (hide HBM latency under compute)
      s16x8 pk0, pk1;
      s16x4 pvj[4];
      if (pre) {
        const int kv1 = (tile + 1) * 64;
        const s16x8* ks = (const s16x8*)(Kp + (kv1 + krow) * 64 + kseg * 16);
        pk0 = ks[0];
        pk1 = ks[1];
#pragma unroll
        for (int j = 0; j < 4; ++j)
          pvj[j] = *(const s16x4*)(Vp + (kv1 + kvb_ * 4 + j) * 64 + dhb * 4);
      }

      // S^T = K Q^T : s4[f][r] = S[kv = f*16+g*4+r][q = ln]
      f32x4 s4[4] = {};
#pragma unroll
      for (int st = 0; st < 2; ++st)
#pragma unroll
        for (int f = 0; f < 4; ++f) {
          bf16x8 kf = bc8(kV[buf * 576 + (f * 16 + ln) * 9 + st * 4 + g]);
          s4[f] = __builtin_amdgcn_mfma_f32_16x16x32_bf16(kf, qf[st], s4[f], 0, 0, 0);
        }
      if (tile == ntile - 1) {  // diagonal: mask kv > q
#pragma unroll
        for (int f = 0; f < 4; ++f)
#pragma unroll
          for (int r = 0; r < 4; ++r)
            if (f * 16 + g * 4 + r > w * 16 + ln) s4[f][r] = -1e30f;
      }

      // per-lane online softmax (q = ln; partner lanes differ only in g)
      float fx[4];
#pragma unroll
      for (int f = 0; f < 4; ++f)
        fx[f] = fmaxf(fmaxf(s4[f][0], s4[f][1]), fmaxf(s4[f][2], s4[f][3]));
      float mt = fmaxf(fmaxf(fx[0], fx[1]), fmaxf(fx[2], fx[3]));
      mt = fmaxf(mt, __shfl_xor(mt, 16));
      mt = fmaxf(mt, __shfl_xor(mt, 32));
      const float mn = fmaxf(mrow, mt);
      const float alpha = __expf(mrow - mn);
      f32x4 p4[4];
      float sf[4];
#pragma unroll
      for (int f = 0; f < 4; ++f) {
#pragma unroll
        for (int r = 0; r < 4; ++r) p4[f][r] = __expf(s4[f][r] - mn);
        sf[f] = (p4[f][0] + p4[f][1]) + (p4[f][2] + p4[f][3]);
      }
      float ps = (sf[0] + sf[1]) + (sf[2] + sf[3]);
      ps += __shfl_xor(ps, 16);
      ps += __shfl_xor(ps, 32);
      lrow = lrow * alpha + ps;
      mrow = mn;
#pragma unroll
      for (int f = 0; f < 4; ++f)
#pragma unroll
        for (int r = 0; r < 4; ++r) o[f][r] *= alpha;

      // P -> wave-private LDS rows, packed b64 (kv consecutive over r)
      short* pB = (short*)pV;
#pragma unroll
      for (int f = 0; f < 4; ++f) {
        s16x4 pw;
#pragma unroll
        for (int r = 0; r < 4; ++r) pw[r] = (short)f2bf(p4[f][r]);
        *(s16x4*)(pB + (w * 16 + ln) * 72 + f * 16 + g * 4) = pw;
      }

      // O^T += V^T P : o[f][r] = O[dh = f*16+g*4+r][q = ln]
#pragma unroll
      for (int st = 0; st < 2; ++st) {
        bf16x8 pa = bc8(pV[(w * 16 + ln) * 9 + st * 4 + g]);
#pragma unroll
        for (int f = 0; f < 4; ++f) {
          bf16x8 vf = bc8(vtV[buf * 576 + (f * 16 + ln) * 9 + st * 4 + g]);
          o[f] = __builtin_amdgcn_mfma_f32_16x16x32_bf16(vf, pa, o[f], 0, 0, 0);
        }
      }

      if (pre) {  // write prefetched tile into the other buffer
        const int ob_ = buf ^ 1;
        kV[ob_ * 576 + krow * 9 + kseg * 2]     = pk0;
        kV[ob_ * 576 + krow * 9 + kseg * 2 + 1] = pk1;
#pragma unroll
        for (int d = 0; d < 4; ++d) {
          s16x4 wv;
          wv[0] = pvj[0][d]; wv[1] = pvj[1][d]; wv[2] = pvj[2][d]; wv[3] = pvj[3][d];
          // per-buffer size = 64 rows * 72 shorts = 4608 shorts (NOT 9216 - r2 bugfix)
          *(s16x4*)((short*)vtV + ob_ * 4608 + (dhb * 4 + d) * 72 + kvb_ * 4) = wv;
        }
        __syncthreads();
      }
    }

    // epilogue: lane holds O^T[dh = f*16+g*4+r][q = ln], l for q = ln
    const float inv = 1.0f / lrow;
    const int qrow = b * 2048 + q0 + w * 16 + ln;
#pragma unroll
    for (int f = 0; f < 4; ++f) {
      s16x4 ov;
#pragma unroll
      for (int r = 0; r < 4; ++r) ov[r] = (short)f2bf(o[f][r] * inv);
      *(s16x4*)(ob + (size_t)qrow * 1024 + h * 64 + f * 16 + g * 4) = ov;
    }
  }
}

extern "C" void kernel_launch(void* const* d_in, const int* in_sizes, int n_in,
                              void* d_out, int out_size, void* d_ws, size_t ws_size,
                              hipStream_t stream) {
  (void)in_sizes; (void)n_in; (void)out_size; (void)ws_size;
  const float* x  = (const float*)d_in[0];
  const float* Wq = (const float*)d_in[1];
  const float* bq = (const float*)d_in[2];
  const float* Wk = (const float*)d_in[3];
  const float* bk = (const float*)d_in[4];
  const float* Wv = (const float*)d_in[5];
  const float* bv = (const float*)d_in[6];
  const float* Wo = (const float*)d_in[7];
  const float* bo = (const float*)d_in[8];
  float* out = (float*)d_out;

  unsigned short* ws  = (unsigned short*)d_ws;
  unsigned short* xb  = ws;
  unsigned short* wtb = ws + 4194304;
  unsigned short* qbuf= ws + 8388608;
  unsigned short* kbuf= qbuf + 4194304;
  unsigned short* vbuf= kbuf + 4194304;
  unsigned short* ab  = vbuf + 4194304;

  cast_x_k<<<2048, 256, 0, stream>>>(x, xb);
  transpose_w_k<<<dim3(16, 16, 4), 256, 0, stream>>>(Wq, Wk, Wv, Wo, wtb);
  gemm_k<0><<<dim3(8, 64), 256, 0, stream>>>(xb, wtb,           bq, nullptr,       qbuf);
  gemm_k<1><<<dim3(8, 64), 256, 0, stream>>>(xb, wtb + 1048576, bk, out + 4194304, kbuf);
  gemm_k<1><<<dim3(8, 64), 256, 0, stream>>>(xb, wtb + 2097152, bv, out + 8388608, vbuf);
  attn_k<<<dim3(16, 32), 256, 0, stream>>>(qbuf, kbuf, vbuf, ab);
  gemm_k<2><<<dim3(8, 64), 256, 0, stream>>>(ab, wtb + 3145728, bo, out, nullptr);
}

// Round 4
// 152.372 us; speedup vs baseline: 1.5581x; 1.0059x over previous
//
#include <hip/hip_runtime.h>

typedef float  f32x4  __attribute__((ext_vector_type(4)));
typedef __bf16 bf16x8 __attribute__((ext_vector_type(8)));
typedef short  s16x8  __attribute__((ext_vector_type(8)));
typedef short  s16x4  __attribute__((ext_vector_type(4)));

static __device__ __forceinline__ unsigned short f2bf(float f) {
  return __builtin_bit_cast(unsigned short, (__bf16)f);
}
static __device__ __forceinline__ bf16x8 bc8(s16x8 v) {
  return __builtin_bit_cast(bf16x8, v);
}

// async global->LDS, 16B per lane. LDS dest must be wave-uniform base + lane*16.
static __device__ __forceinline__ void gl2lds16(const unsigned short* g, unsigned short* l) {
  __builtin_amdgcn_global_load_lds(
      (const __attribute__((address_space(1))) unsigned int*)g,
      (__attribute__((address_space(3))) unsigned int*)l, 16, 0, 0);
}

// ---------------- cast x (fp32 -> bf16) ----------------
__global__ void cast_x_k(const float* __restrict__ x, unsigned short* __restrict__ xb) {
  int i = (blockIdx.x * 256 + threadIdx.x) * 8;
  float4 a = *(const float4*)(x + i);
  float4 b = *(const float4*)(x + i + 4);
  s16x8 o;
  o[0] = (short)f2bf(a.x); o[1] = (short)f2bf(a.y);
  o[2] = (short)f2bf(a.z); o[3] = (short)f2bf(a.w);
  o[4] = (short)f2bf(b.x); o[5] = (short)f2bf(b.y);
  o[6] = (short)f2bf(b.z); o[7] = (short)f2bf(b.w);
  *(s16x8*)(xb + i) = o;
}

// ------------- transpose W (1024x1024 fp32 k-major) -> WT bf16 (n-major) -------------
__global__ void transpose_w_k(const float* __restrict__ W0, const float* __restrict__ W1,
                              const float* __restrict__ W2, const float* __restrict__ W3,
                              unsigned short* __restrict__ wtb) {
  const float* W = blockIdx.z == 0 ? W0 : blockIdx.z == 1 ? W1 : blockIdx.z == 2 ? W2 : W3;
  unsigned short* out = wtb + (size_t)blockIdx.z * 1048576;
  __shared__ unsigned short tl[64][72];
  const int t = threadIdx.x;
  const int kt = blockIdx.y * 64, nt = blockIdx.x * 64;
  const int row = t >> 2, seg = t & 3;
  const float* src = W + (kt + row) * 1024 + nt + seg * 16;
#pragma unroll
  for (int q = 0; q < 4; ++q) {
    float4 v = *(const float4*)(src + q * 4);
    tl[seg * 16 + q * 4 + 0][row] = f2bf(v.x);
    tl[seg * 16 + q * 4 + 1][row] = f2bf(v.y);
    tl[seg * 16 + q * 4 + 2][row] = f2bf(v.z);
    tl[seg * 16 + q * 4 + 3][row] = f2bf(v.w);
  }
  __syncthreads();
  unsigned short* dst = out + (nt + row) * 1024 + kt + seg * 16;
  *(s16x8*)dst       = *(const s16x8*)&tl[row][seg * 16];
  *(s16x8*)(dst + 8) = *(const s16x8*)&tl[row][seg * 16 + 8];
}

static __device__ __forceinline__ int trans_ix(int m, int n) {
  int b = m >> 11, tt = m & 2047, h = n >> 6, dh = n & 63;
  return ((b << 4) + h) * 131072 + tt * 64 + dh;
}

// ---------------- GEMM (m97 structure): C(4096 x N) = A @ BT^T + bias ----------------
// MODE 0: fused QKV (N=3072, BM=128): q (bf16,*0.125), k,v (bf16 + fp32 to d_out)
// MODE 2: O-proj   (N=1024, BM=64): fp32 out
template <int MODE, int BM>
__global__ __launch_bounds__(256) void gemm2_k(const unsigned short* __restrict__ A,
                                               const unsigned short* __restrict__ BT,
                                               const float* __restrict__ b0,
                                               const float* __restrict__ b1,
                                               const float* __restrict__ b2,
                                               float* __restrict__ outF,
                                               unsigned short* __restrict__ oq,
                                               unsigned short* __restrict__ ok,
                                               unsigned short* __restrict__ ov) {
  constexpr int MI = BM / 32;  // m-frags per wave
  __shared__ unsigned short aS[2][BM * 32];
  __shared__ unsigned short bS[2][128 * 32];
  const int t = threadIdx.x;
  const int lane = t & 63, ln = lane & 15, g = lane >> 4;
  const int w = t >> 6, wm = w >> 1, wn = w & 1;
  const int bn0 = blockIdx.x * 128, bm0 = blockIdx.y * BM;
  f32x4 acc[MI][4] = {};

  auto stage = [&](int ks, int buf) {
    const int kk = ks * 32;
#pragma unroll
    for (int q = 0; q < BM / 64; ++q) {
      int e = q * 256 + t;
      int row = e >> 2, c8 = e & 3;
      gl2lds16(A + (size_t)(bm0 + row) * 1024 + kk + c8 * 8, &aS[buf][e * 8]);
    }
#pragma unroll
    for (int q = 0; q < 2; ++q) {
      int e = q * 256 + t;
      int row = e >> 2, c8 = e & 3;
      gl2lds16(BT + (size_t)(bn0 + row) * 1024 + kk + c8 * 8, &bS[buf][e * 8]);
    }
  };

  stage(0, 0);
  for (int ks = 0; ks < 32; ++ks) {
    const int buf = ks & 1;
    __syncthreads();  // waits vmcnt(0): stage for this buf complete
    if (ks + 1 < 32) stage(ks + 1, buf ^ 1);
    bf16x8 af[MI], bfv[4];
#pragma unroll
    for (int i = 0; i < MI; ++i)
      af[i] = bc8(*(const s16x8*)&aS[buf][(wm * (BM / 2) + i * 16 + ln) * 32 + g * 8]);
#pragma unroll
    for (int i = 0; i < 4; ++i)
      bfv[i] = bc8(*(const s16x8*)&bS[buf][(wn * 64 + i * 16 + ln) * 32 + g * 8]);
#pragma unroll
    for (int mi = 0; mi < MI; ++mi)
#pragma unroll
      for (int ni = 0; ni < 4; ++ni)
        acc[mi][ni] = __builtin_amdgcn_mfma_f32_16x16x32_bf16(af[mi], bfv[ni], acc[mi][ni], 0, 0, 0);
  }

#pragma unroll
  for (int ni = 0; ni < 4; ++ni) {
    const int n = bn0 + wn * 64 + ni * 16 + ln;
    const int n1 = n & 1023;
    const float* bp = (MODE == 2) ? b0 : (n < 1024 ? b0 : (n < 2048 ? b1 : b2));
    const float bias = bp[n1];
#pragma unroll
    for (int mi = 0; mi < MI; ++mi)
#pragma unroll
      for (int r = 0; r < 4; ++r) {
        const int m = bm0 + wm * (BM / 2) + mi * 16 + g * 4 + r;
        const float v = acc[mi][ni][r] + bias;
        if (MODE == 2) {
          outF[(size_t)m * 1024 + n] = v;
        } else {
          const int ix = trans_ix(m, n1);
          if (n < 1024) {
            oq[ix] = f2bf(v * 0.125f);
          } else if (n < 2048) {
            ok[ix] = f2bf(v);
            outF[4194304 + ix] = v;
          } else {
            ov[ix] = f2bf(v);
            outF[8388608 + ix] = v;
          }
        }
      }
  }
}

// ---------------- flash attention v3 ----------------
// Swapped operands: S^T = mfma(K,Q), O^T = mfma(V^T,P). Wave = 32 q-rows (2 frags),
// block = 4 waves = 128 q-rows. Grid 512 (1D, XCD-swizzled: bh&7 == wgid&7, big
// q-tiles first). K/V double-buffered LDS, reg-prefetch issued before compute.
__global__ __launch_bounds__(256) void attn_k(const unsigned short* __restrict__ qb,
                                              const unsigned short* __restrict__ kb,
                                              const unsigned short* __restrict__ vb,
                                              unsigned short* __restrict__ ob) {
  __shared__ s16x8 kV[2 * 64 * 9];   // [buf][kv][slot]  row stride 144B
  __shared__ s16x8 vtV[2 * 64 * 9];  // [buf][dh][slot]  (V transposed)
  __shared__ s16x8 pV[128 * 9];      // [q-local][slot]  wave-private rows
  const int t = threadIdx.x;
  const int lane = t & 63, ln = lane & 15, g = lane >> 4;
  const int w = t >> 6;
  // swizzled block id: wg = (bh&7) | r<<3 ; r = (bh>>3)*16 + (15-qblk)
  const unsigned wg = blockIdx.x;
  const int r_ = wg >> 3;
  const int bh = (wg & 7) + 8 * (r_ >> 4);
  const int qblk = 15 - (r_ & 15);
  const int b = bh >> 4, h = bh & 15;
  const unsigned short* Qp = qb + (size_t)bh * 131072;
  const unsigned short* Kp = kb + (size_t)bh * 131072;
  const unsigned short* Vp = vb + (size_t)bh * 131072;
  const int q0 = qblk * 128;
  const int ntile = 2 * qblk + 2;

  const int krow = t >> 2, kseg = t & 3;   // K stage mapping
  const int kvb_ = t >> 4, dhb = t & 15;   // V stage mapping

  bf16x8 qf[2][2];
#pragma unroll
  for (int qs = 0; qs < 2; ++qs) {
    const unsigned short* qrow = Qp + (q0 + w * 32 + qs * 16 + ln) * 64 + g * 8;
    qf[qs][0] = bc8(*(const s16x8*)qrow);
    qf[qs][1] = bc8(*(const s16x8*)(qrow + 32));
  }
  f32x4 o[2][4] = {};
  float mrow[2] = {-1e30f, -1e30f};
  float lrow[2] = {0.f, 0.f};

  {  // prologue: stage tile 0 into buf 0
    const s16x8* ks = (const s16x8*)(Kp + krow * 64 + kseg * 16);
    kV[krow * 9 + kseg * 2]     = ks[0];
    kV[krow * 9 + kseg * 2 + 1] = ks[1];
    s16x4 vj[4];
#pragma unroll
    for (int j = 0; j < 4; ++j)
      vj[j] = *(const s16x4*)(Vp + (kvb_ * 4 + j) * 64 + dhb * 4);
#pragma unroll
    for (int dd = 0; dd < 4; ++dd) {
      const int d = (dd + dhb) & 3;  // bank-spread write order
      s16x4 wv;
      wv[0] = vj[0][d]; wv[1] = vj[1][d]; wv[2] = vj[2][d]; wv[3] = vj[3][d];
      *(s16x4*)((short*)vtV + (dhb * 4 + d) * 72 + kvb_ * 4) = wv;
    }
  }
  __syncthreads();

  for (int tile = 0; tile < ntile; ++tile) {
    const int buf = tile & 1;
    const bool pre = (tile + 1) < ntile;
    s16x8 pk0, pk1;
    s16x4 pvj[4];
    if (pre) {  // issue next tile's global loads (land after PV)
      const int kv1 = (tile + 1) * 64;
      const s16x8* ks = (const s16x8*)(Kp + (kv1 + krow) * 64 + kseg * 16);
      pk0 = ks[0];
      pk1 = ks[1];
#pragma unroll
      for (int j = 0; j < 4; ++j)
        pvj[j] = *(const s16x4*)(Vp + (kv1 + kvb_ * 4 + j) * 64 + dhb * 4);
    }

    bf16x8 kf[2][4];
#pragma unroll
    for (int st = 0; st < 2; ++st)
#pragma unroll
      for (int f = 0; f < 4; ++f)
        kf[st][f] = bc8(kV[buf * 576 + (f * 16 + ln) * 9 + st * 4 + g]);

#pragma unroll
    for (int qs = 0; qs < 2; ++qs) {
      // S^T: s4[f][r] = S[kv = tile*64 + f*16+g*4+r][q = q0 + w*32+qs*16+ln]
      f32x4 s4[4] = {};
#pragma unroll
      for (int st = 0; st < 2; ++st)
#pragma unroll
        for (int f = 0; f < 4; ++f)
          s4[f] = __builtin_amdgcn_mfma_f32_16x16x32_bf16(kf[st][f], qf[qs][st], s4[f], 0, 0, 0);

      const int qg = q0 + w * 32 + qs * 16 + ln;
      if (tile * 64 + 63 > q0 + w * 32 + qs * 16) {  // diagonal: mask kv > q
#pragma unroll
        for (int f = 0; f < 4; ++f)
#pragma unroll
          for (int rr = 0; rr < 4; ++rr)
            if (tile * 64 + f * 16 + g * 4 + rr > qg) s4[f][rr] = -1e30f;
      }

      // per-lane online softmax
      float fx[4];
#pragma unroll
      for (int f = 0; f < 4; ++f)
        fx[f] = fmaxf(fmaxf(s4[f][0], s4[f][1]), fmaxf(s4[f][2], s4[f][3]));
      float mt = fmaxf(fmaxf(fx[0], fx[1]), fmaxf(fx[2], fx[3]));
      mt = fmaxf(mt, __shfl_xor(mt, 16));
      mt = fmaxf(mt, __shfl_xor(mt, 32));
      const float mn = fmaxf(mrow[qs], mt);
      const float alpha = __expf(mrow[qs] - mn);
      f32x4 p4[4];
      float sf[4];
#pragma unroll
      for (int f = 0; f < 4; ++f) {
#pragma unroll
        for (int rr = 0; rr < 4; ++rr) p4[f][rr] = __expf(s4[f][rr] - mn);
        sf[f] = (p4[f][0] + p4[f][1]) + (p4[f][2] + p4[f][3]);
      }
      float ps = (sf[0] + sf[1]) + (sf[2] + sf[3]);
      ps += __shfl_xor(ps, 16);
      ps += __shfl_xor(ps, 32);
      lrow[qs] = lrow[qs] * alpha + ps;
      mrow[qs] = mn;
#pragma unroll
      for (int f = 0; f < 4; ++f)
#pragma unroll
        for (int rr = 0; rr < 4; ++rr) o[qs][f][rr] *= alpha;

      // P -> wave-private LDS rows (packed b64; intra-wave, no barrier needed)
      short* pB = (short*)pV;
#pragma unroll
      for (int f = 0; f < 4; ++f) {
        s16x4 pw;
#pragma unroll
        for (int rr = 0; rr < 4; ++rr) pw[rr] = (short)f2bf(p4[f][rr]);
        *(s16x4*)(pB + (w * 32 + qs * 16 + ln) * 72 + f * 16 + g * 4) = pw;
      }
    }

    // O^T += V^T P
#pragma unroll
    for (int st = 0; st < 2; ++st) {
      bf16x8 pa0 = bc8(pV[(w * 32 + ln) * 9 + st * 4 + g]);
      bf16x8 pa1 = bc8(pV[(w * 32 + 16 + ln) * 9 + st * 4 + g]);
#pragma unroll
      for (int f = 0; f < 4; ++f) {
        bf16x8 vf = bc8(vtV[buf * 576 + (f * 16 + ln) * 9 + st * 4 + g]);
        o[0][f] = __builtin_amdgcn_mfma_f32_16x16x32_bf16(vf, pa0, o[0][f], 0, 0, 0);
        o[1][f] = __builtin_amdgcn_mfma_f32_16x16x32_bf16(vf, pa1, o[1][f], 0, 0, 0);
      }
    }

    if (pre) {  // write prefetched tile into the other buffer
      const int ob_ = buf ^ 1;
      kV[ob_ * 576 + krow * 9 + kseg * 2]     = pk0;
      kV[ob_ * 576 + krow * 9 + kseg * 2 + 1] = pk1;
#pragma unroll
      for (int dd = 0; dd < 4; ++dd) {
        const int d = (dd + dhb) & 3;
        s16x4 wv;
        wv[0] = pvj[0][d]; wv[1] = pvj[1][d]; wv[2] = pvj[2][d]; wv[3] = pvj[3][d];
        *(s16x4*)((short*)vtV + ob_ * 4608 + (dhb * 4 + d) * 72 + kvb_ * 4) = wv;
      }
      __syncthreads();
    }
  }

  // epilogue: o[qs][f][r] = O^T[dh = f*16+g*4+r][q], q = q0 + w*32 + qs*16 + ln
#pragma unroll
  for (int qs = 0; qs < 2; ++qs) {
    const float inv = 1.0f / lrow[qs];
    const int qrow = b * 2048 + q0 + w * 32 + qs * 16 + ln;
#pragma unroll
    for (int f = 0; f < 4; ++f) {
      s16x4 ov;
#pragma unroll
      for (int rr = 0; rr < 4; ++rr) ov[rr] = (short)f2bf(o[qs][f][rr] * inv);
      *(s16x4*)(ob + (size_t)qrow * 1024 + h * 64 + f * 16 + g * 4) = ov;
    }
  }
}

extern "C" void kernel_launch(void* const* d_in, const int* in_sizes, int n_in,
                              void* d_out, int out_size, void* d_ws, size_t ws_size,
                              hipStream_t stream) {
  (void)in_sizes; (void)n_in; (void)out_size; (void)ws_size;
  const float* x  = (const float*)d_in[0];
  const float* Wq = (const float*)d_in[1];
  const float* bq = (const float*)d_in[2];
  const float* Wk = (const float*)d_in[3];
  const float* bk = (const float*)d_in[4];
  const float* Wv = (const float*)d_in[5];
  const float* bv = (const float*)d_in[6];
  const float* Wo = (const float*)d_in[7];
  const float* bo = (const float*)d_in[8];
  float* out = (float*)d_out;

  unsigned short* ws  = (unsigned short*)d_ws;
  unsigned short* xb  = ws;              // 4,194,304 bf16
  unsigned short* wtb = ws + 4194304;    // 4 x 1,048,576 (Wq^T,Wk^T,Wv^T,Wo^T)
  unsigned short* qbuf = ws + 8388608;
  unsigned short* kbuf = qbuf + 4194304;
  unsigned short* vbuf = kbuf + 4194304;
  unsigned short* ab   = vbuf + 4194304;

  cast_x_k<<<2048, 256, 0, stream>>>(x, xb);
  transpose_w_k<<<dim3(16, 16, 4), 256, 0, stream>>>(Wq, Wk, Wv, Wo, wtb);
  gemm2_k<0, 128><<<dim3(24, 32), 256, 0, stream>>>(xb, wtb, bq, bk, bv, out, qbuf, kbuf, vbuf);
  attn_k<<<512, 256, 0, stream>>>(qbuf, kbuf, vbuf, ab);
  gemm2_k<2, 64><<<dim3(8, 64), 256, 0, stream>>>(ab, wtb + 3145728, bo, bo, bo, out,
                                                  nullptr, nullptr, nullptr);
}